// Round 12
// baseline (29.970 us; speedup 1.0000x reference)
//
#include <hip/hip_runtime.h>
#include <math.h>

// Problem constants (fixed by setup_inputs)
#define BATCH 4
#define NPTS  2048
#define CHAN  32
#define CONVF 332.07156

#define ROWS 8            // rows per group
#define GROUPS 4          // groups per block (32 rows/block)
#define THREADS 256
#define NBLOCKS ((BATCH * NPTS / (ROWS * GROUPS)) * 2)  // 512: (rowblk, jhalf)
#define NQUADS (BATCH * NPTS / 4)
#define QPB (NPTS / 4)    // 512 quads per row

typedef float f4v __attribute__((ext_vector_type(4)));

// --- Kernel A: pack i-side structs + quad-transposed j-side planes --------
__global__ void pack_points(const float* __restrict__ X,
                            const float* __restrict__ embs,
                            const float* __restrict__ qs,
                            const float* __restrict__ Ps,
                            const float* __restrict__ sfw,
                            float4* __restrict__ pk,   // (B*N*2) i-side
                            float* __restrict__ ai,    // (B*N)
                            float* __restrict__ pkT) { // (8*NQUADS*4) j-side
    int idx = blockIdx.x * blockDim.x + threadIdx.x;
    if (idx >= BATCH * NPTS) return;
    int n = idx & (NPTS - 1);
    const float* e = embs + (size_t)idx * CHAN;
    float sj = 0.f, si = 0.f;
#pragma unroll
    for (int k = 0; k < CHAN; ++k) {
        float ev = e[k];
        sj = fmaf(ev, sfw[k], sj);
        si = fmaf(ev, sfw[CHAN + k], si);
    }
    float xv = X[idx * 3 + 0], yv = X[idx * 3 + 1], zv = X[idx * 3 + 2];
    float qv = qs[n];
    float Px = Ps[n * 3 + 0], Py = Ps[n * 3 + 1], Pz = Ps[n * 3 + 2];

    float4 a, bb;
    a.x = xv; a.y = yv; a.z = zv; a.w = qv;
    bb.x = Px; bb.y = Py; bb.z = Pz; bb.w = sj;
    pk[idx * 2 + 0] = a;
    pk[idx * 2 + 1] = bb;
    ai[idx] = si;

    int q = idx >> 2, t = idx & 3;
    pkT[(0 * NQUADS + q) * 4 + t] = xv;
    pkT[(1 * NQUADS + q) * 4 + t] = yv;
    pkT[(2 * NQUADS + q) * 4 + t] = zv;
    pkT[(3 * NQUADS + q) * 4 + t] = qv;
    pkT[(4 * NQUADS + q) * 4 + t] = Px;
    pkT[(5 * NQUADS + q) * 4 + t] = Py;
    pkT[(6 * NQUADS + q) * 4 + t] = Pz;
    pkT[(7 * NQUADS + q) * 4 + t] = sj;
}

// --- Kernel B: 4-group register pipeline: prefetch g+1 || compute g -------
__global__ __launch_bounds__(THREADS, 2) void pair_energy(
    const float4* __restrict__ pk,   // (B*N*2)  i-side
    const float* __restrict__ ai,    // (B*N)
    const f4v* __restrict__ pkT4,    // (8*NQUADS) j-side planes
    const f4v* __restrict__ mask4,   // (B*N*N/4)
    const float* __restrict__ sfw,   // (2C+1,)
    double* __restrict__ partials)   // (NBLOCKS,)
{
    const float wd = sfw[2 * CHAN];
    const int rowblk = blockIdx.x >> 1;
    const int jhalf  = blockIdx.x & 1;
    const int rowbase = rowblk * (ROWS * GROUPS);  // 32 rows per block
    const int b  = rowbase >> 11;
    const int tid = threadIdx.x;
    const int jq = jhalf * THREADS + tid;          // quad in row, 0..511
    const int qidx = b * QPB + jq;

    // ---- j-side planes: loaded ONCE, reused for all 4 groups ----
    f4v vx  = pkT4[0 * NQUADS + qidx];
    f4v vy  = pkT4[1 * NQUADS + qidx];
    f4v vz  = pkT4[2 * NQUADS + qidx];
    f4v vq  = pkT4[3 * NQUADS + qidx];
    f4v vpx = pkT4[4 * NQUADS + qidx];
    f4v vpy = pkT4[5 * NQUADS + qidx];
    f4v vpz = pkT4[6 * NQUADS + qidx];
    f4v vaj = pkT4[7 * NQUADS + qidx];

    f4v mA[ROWS], mB[ROWS];
    double acc = 0.0;

    // prologue: stage group 0 into A
#pragma unroll
    for (int r = 0; r < ROWS; ++r)
        mA[r] = __builtin_nontemporal_load(
            &mask4[(size_t)(rowbase + r) * QPB + jq]);

    // pipeline: prefetch group g+1 into alternate buffer, compute group g
#pragma unroll
    for (int g = 0; g < GROUPS; ++g) {
        const f4v* cur = (g & 1) ? mB : mA;   // compile-time after unroll
        f4v*       nxt = (g & 1) ? mA : mB;
        if (g + 1 < GROUPS) {
#pragma unroll
            for (int r = 0; r < ROWS; ++r)
                nxt[r] = __builtin_nontemporal_load(
                    &mask4[(size_t)(rowbase + (g + 1) * ROWS + r) * QPB + jq]);
        }
        // pin: prefetch issued before compute, compute can't hoist above
        __builtin_amdgcn_sched_barrier(0);

#pragma unroll
        for (int r = 0; r < ROWS; ++r) {
            const int row = rowbase + g * ROWS + r;
            // i-side: block-uniform -> scalar loads
            float4 a = pk[row * 2 + 0];
            float4 p = pk[row * 2 + 1];
            float aw = ai[row];
            float cP = 1e-6f * (p.x + p.y + p.z);   // eps-dot, row-constant
            float es = 0.f;
#pragma unroll
            for (int t = 0; t < 4; ++t) {
                float dx = vx[t] - a.x;
                float dy = vy[t] - a.y;
                float dz = vz[t] - a.z;
                float d2 = fmaf(dx, dx, fmaf(dy, dy, fmaf(dz, dz, 3e-6f)));
                float invD = __builtin_amdgcn_rsqf(d2);
                float OqP = fmaf(dx, p.x, fmaf(dy, p.y, fmaf(dz, p.z, cP)));
                float OPP = fmaf(p.x, vpx[t], fmaf(p.y, vpy[t], p.z * vpz[t]));
                float Q12 = a.w * vq[t];
                float sf  = fmaf(invD, wd, aw + vaj[t]);
                float invD2 = invD * invD;
                float invD4 = invD2 * invD2;
                float invD5 = invD4 * invD;
                float invD6 = invD4 * invD2;
                float E = fmaf(Q12 * invD, sf,
                          fmaf(OqP, invD5, OPP * invD6));
                es = fmaf(cur[r][t], E, es);
            }
            acc += (double)es;
        }
    }

    // ---- wave shuffle reduce + 4-entry LDS combine ----
#pragma unroll
    for (int s = 32; s > 0; s >>= 1)
        acc += __shfl_xor(acc, s, 64);

    __shared__ double wsum[THREADS / 64];
    const int lane = tid & 63;
    const int wid  = tid >> 6;
    if (lane == 0) wsum[wid] = acc;
    __syncthreads();
    if (tid == 0)
        partials[blockIdx.x] = wsum[0] + wsum[1] + wsum[2] + wsum[3];
}

// --- Kernel C: final reduction + scale + NaN guard ------------------------
__global__ void finalize(const double* __restrict__ partials, int n,
                         float* __restrict__ out) {
    __shared__ double sdata[256];
    double a = 0.0;
    for (int i = threadIdx.x; i < n; i += 256) a += partials[i];
    sdata[threadIdx.x] = a;
    __syncthreads();
#pragma unroll
    for (int s = 128; s > 0; s >>= 1) {
        if (threadIdx.x < s) sdata[threadIdx.x] += sdata[threadIdx.x + s];
        __syncthreads();
    }
    if (threadIdx.x == 0) {
        double tot = sdata[0] * (double)CONVF * 0.5;
        float f = (float)tot;
        out[0] = isnan(f) ? 1e-6f : f;
    }
}

extern "C" void kernel_launch(void* const* d_in, const int* in_sizes, int n_in,
                              void* d_out, int out_size, void* d_ws, size_t ws_size,
                              hipStream_t stream) {
    const float* X    = (const float*)d_in[0];
    const float* embs = (const float*)d_in[1];
    const float* qs   = (const float*)d_in[2];
    const float* Ps   = (const float*)d_in[3];
    const float* mask = (const float*)d_in[4];
    const float* sfw  = (const float*)d_in[5];
    float* out = (float*)d_out;

    // workspace: [ partials double[NBLOCKS] | pk float4[B*N*2] | ai float[B*N]
    //            | pkT float[8*NQUADS*4] ]
    double* partials = (double*)d_ws;
    float4* pk  = (float4*)(partials + NBLOCKS);
    float*  ai  = (float*)(pk + BATCH * NPTS * 2);
    float*  pkT = ai + BATCH * NPTS;

    pack_points<<<(BATCH * NPTS + 255) / 256, 256, 0, stream>>>(X, embs, qs, Ps, sfw,
                                                                pk, ai, pkT);
    pair_energy<<<NBLOCKS, THREADS, 0, stream>>>(pk, ai, (const f4v*)pkT,
                                                 (const f4v*)mask, sfw, partials);
    finalize<<<1, 256, 0, stream>>>(partials, NBLOCKS, out);
}